// Round 8
// baseline (523.022 us; speedup 1.0000x reference)
//
#include <hip/hip_runtime.h>
#include <hip/hip_bf16.h>

// ---------------- problem constants ----------------
#define NI 1152
// conv2 GEMM view: M per pos = 256 (batch), N=256 (oc), K=82 taps (81+1 zero) x 32 ic per ks

typedef __attribute__((ext_vector_type(8))) _Float16 f16x8;
typedef __attribute__((ext_vector_type(4))) float f32x4;
typedef __attribute__((ext_vector_type(8))) unsigned short u16x8;
typedef __attribute__((ext_vector_type(4))) unsigned short u16x4;

// ws layout (bytes). Phase-1 buffers (w6,h3,wT1) alias under uhat; pp is OUTSIDE
// (postconv reads pp while writing UH).
static const size_t UHAT_OFF = 0;                        // bf16 1152*10*256*16 = 94,371,840
static const size_t W6_OFF   = 0;                        // f16 82*8*16*512 = 10,749,952 B
static const size_t H3_OFF   = 10750976UL;               // f16 8*400*4*256*8 = 52,428,800 B
static const size_t WT1_OFF  = 63179776UL;               // f32 81*256 (ends 63,262,720 < UHAT end)
static const size_t PP_OFF   = 94371840UL;               // f32 9216*256 = 9,437,184
static const size_t SP_OFF   = 103809024UL;              // f32 144*256*160 = 23,592,960
static const size_t L_OFF    = 127401984UL;              // f32 256*1152*10 = 11,796,480
static const size_t V_OFF    = 139198464UL;              // f32 256*160

__device__ __forceinline__ unsigned short f2bf(float x) {
    unsigned u = __builtin_bit_cast(unsigned, x);
    u += 0x7fffu + ((u >> 16) & 1u);
    return (unsigned short)(u >> 16);
}
__device__ __forceinline__ float bf2f(unsigned short h) {
    return __builtin_bit_cast(float, (unsigned)h << 16);
}
__device__ __forceinline__ void atomAddF(float* p, float v) {
    __hip_atomic_fetch_add(p, v, __ATOMIC_RELAXED, __HIP_MEMORY_SCOPE_AGENT);
}

#define GLD16(gsrc, ldst)                                                      \
    __builtin_amdgcn_global_load_lds(                                          \
        (__attribute__((address_space(1))) const void*)(gsrc),                 \
        (__attribute__((address_space(3))) void*)(ldst), 16, 0, 0)

// ---------------- weight prep: pc_w [oc][ic*81+tap] -> w6 frag-linear ----------------
// w6 linear: (((tap*8+ks)*16 + og)*64 + lane)*8 + icl
//   og=oc>>4, fr=oc&15, lane=kch*16+fr, ic=ks*32+kch*8+icl
__global__ __launch_bounds__(256) void k_prep_w(const float* __restrict__ pcw,
                                                _Float16* __restrict__ w6) {
    __shared__ float sl[5184];
    int oc  = blockIdx.x;       // 256
    int ic0 = blockIdx.y * 64;  // 4 chunks
    const float* src = pcw + (size_t)oc * 20736 + (size_t)ic0 * 81;
    for (int j = threadIdx.x; j < 5184; j += 256) sl[j] = src[j];
    __syncthreads();
    int og = oc >> 4, fr = oc & 15;
    for (int t = threadIdx.x; t < 5184; t += 256) {
        int tap = t >> 6, i = t & 63;
        int ic = ic0 + i;
        int ks = ic >> 5, kch = (ic >> 3) & 3, icl = ic & 7;
        int lane = kch * 16 + fr;
        w6[(((size_t)(tap * 8 + ks) * 16 + og) * 64 + lane) * 8 + icl] =
            (_Float16)sl[i * 81 + tap];
    }
}

// conv1_w [oc][81] -> wT1 [t][oc]
__global__ void k_transpose_w1(const float* __restrict__ w, float* __restrict__ wT) {
    int t = blockIdx.x, oc = threadIdx.x;
    wT[t * 256 + oc] = w[oc * 81 + t];
}

// ---------------- conv1 + relu -> h3[ks][y][x][p][b][8] f16 ----------------
__global__ __launch_bounds__(256) void k_conv1(const float* __restrict__ x,
                                               const float* __restrict__ wT1,
                                               const float* __restrict__ bias,
                                               _Float16* __restrict__ h3) {
    __shared__ _Float16 hs[2][20][256];  // 20KB
    int b  = blockIdx.y;    // 256
    int rp = blockIdx.x;    // 10 row-pairs
    int oc = threadIdx.x;   // 256
    int oy0 = rp * 2;
    const float* xb = x + (size_t)b * 784;
    float bv = bias[oc];
    float acc0[20], acc1[20];
#pragma unroll
    for (int i = 0; i < 20; ++i) { acc0[i] = bv; acc1[i] = bv; }
    for (int ky = 0; ky < 9; ++ky) {
        const float* r0 = xb + (oy0 + ky) * 28;
        const float* r1 = r0 + 28;
        float x0[28], x1[28];
#pragma unroll
        for (int c = 0; c < 28; ++c) { x0[c] = r0[c]; x1[c] = r1[c]; }
#pragma unroll
        for (int kx = 0; kx < 9; ++kx) {
            float w = wT1[(ky * 9 + kx) * 256 + oc];
#pragma unroll
            for (int px = 0; px < 20; ++px) {
                acc0[px] += x0[px + kx] * w;
                acc1[px] += x1[px + kx] * w;
            }
        }
    }
#pragma unroll
    for (int px = 0; px < 20; ++px) {
        hs[0][px][oc] = (_Float16)fmaxf(acc0[px], 0.f);
        hs[1][px][oc] = (_Float16)fmaxf(acc1[px], 0.f);
    }
    __syncthreads();
    for (int cid = threadIdx.x; cid < 1280; cid += 256) {
        int kp = cid & 31;          // ks*4 + p
        int pos = cid >> 5;         // ry*20 + px
        int ry = pos / 20, px2 = pos % 20;
        int ks = kp >> 2, p = kp & 3;
        f16x8 val = *(const f16x8*)&hs[ry][px2][ks * 32 + p * 8];
        _Float16* dst = h3 + ((size_t)((ks * 400 + (oy0 + ry) * 20 + px2) * 4 + p) * 256 + b) * 8;
        *(f16x8*)dst = val;
    }
}

// ---------------- primary caps conv: f16 MFMA, 128x64 wave tiles ----------------
// grid (36 pos, 2 nt, 8 ks); block 256 = 4 waves (2 wm x 2 wn); block tile 256(M=b)x128(N).
// BK=64 (2 taps/iter, 41 iters). A-tap-tile = ONE contiguous 16KB span of h3 (verbatim copy).
// Wave tile 128x64: a[8] x b[4] -> 32 MFMA per 12 ds_read_b128 (LDS-balanced).
__global__ __launch_bounds__(256, 2) void k_conv2_mfma(
    const _Float16* __restrict__ h3, const _Float16* __restrict__ w6,
    float* __restrict__ pp) {
    __shared__ _Float16 As[16384], Bs[8192];  // 32KB + 16KB
    const int pos = blockIdx.x, nt = blockIdx.y, ks = blockIdx.z;
    const int py = pos / 6, px = pos % 6;
    const int l = threadIdx.x & 63;
    const int w = __builtin_amdgcn_readfirstlane((int)(threadIdx.x >> 6));
    const int wm = w >> 1, wn = w & 1;
    const int kch = l >> 4, fr = l & 15;

    f32x4 acc[8][4];
    const f32x4 z = {0.f, 0.f, 0.f, 0.f};
#pragma unroll
    for (int mi = 0; mi < 8; ++mi)
#pragma unroll
        for (int ni = 0; ni < 4; ++ni) acc[mi][ni] = z;

    const size_t h3base = (size_t)ks * 400 * 8192;

    for (int it = 0; it < 41; ++it) {
        const int t0 = 2 * it, t1 = t0 + 1;
        const int tA1 = (t1 > 80) ? 80 : t1;  // clamp A; B tap 81 is zero-padded
#pragma unroll
        for (int tl = 0; tl < 2; ++tl) {
            const int tap  = tl ? t1 : t0;
            const int tapA = tl ? tA1 : t0;
            const int y = 2 * py + tapA / 9, xx = 2 * px + tapA % 9;
            // A: verbatim 16KB span; wave w stages 4KB
            const _Float16* asrc = h3 + h3base + (size_t)(y * 20 + xx) * 8192 + w * 2048 + l * 8;
#pragma unroll
            for (int q = 0; q < 4; ++q)
                GLD16(asrc + q * 512, As + tl * 8192 + w * 2048 + q * 512);
            // B: 8KB (og nt*8..nt*8+8); wave w stages 2KB
            const _Float16* bsrc = w6 + ((size_t)(tap * 8 + ks) * 16 + nt * 8 + w * 2) * 512 + l * 8;
            GLD16(bsrc,       Bs + tl * 4096 + w * 1024);
            GLD16(bsrc + 512, Bs + tl * 4096 + w * 1024 + 512);
        }
        __syncthreads();
#pragma unroll
        for (int tl = 0; tl < 2; ++tl) {
            const _Float16* Ab = As + tl * 8192 + kch * 2048 + (wm * 128 + fr) * 8;
            const _Float16* Bb = Bs + tl * 4096 + wn * 2048 + kch * 128 + fr * 8;
            f16x8 a[8], b[4];
#pragma unroll
            for (int mi = 0; mi < 8; ++mi) a[mi] = *(const f16x8*)(Ab + mi * 128);
#pragma unroll
            for (int ni = 0; ni < 4; ++ni) b[ni] = *(const f16x8*)(Bb + ni * 512);
#pragma unroll
            for (int mi = 0; mi < 8; ++mi)
#pragma unroll
                for (int ni = 0; ni < 4; ++ni)
                    acc[mi][ni] = __builtin_amdgcn_mfma_f32_16x16x32_f16(a[mi], b[ni], acc[mi][ni], 0, 0, 0);
        }
        __syncthreads();
    }
    // epilogue: D row=(lane>>4)*4+reg, col=lane&15; atomic split-K reduce
    const int row0 = kch * 4;
#pragma unroll
    for (int mi = 0; mi < 8; ++mi)
#pragma unroll
        for (int ni = 0; ni < 4; ++ni) {
            int nloc = wn * 64 + ni * 16 + fr;
#pragma unroll
            for (int reg = 0; reg < 4; ++reg) {
                int mloc = wm * 128 + mi * 16 + row0 + reg;
                atomAddF(&pp[((size_t)pos * 256 + mloc) * 256 + nt * 128 + nloc],
                         acc[mi][ni][reg]);
            }
        }
}

// ---------------- fused: bias+squash -> u_hat(bf16 UH) + s0-partials ----------------
// grid (144 it, 4 bt); block 256 = 64 b x 4 og (og = tid&3 -> coalesced UH writes).
__global__ __launch_bounds__(256) void k_postconv(const float* __restrict__ pp,
                                                  const float* __restrict__ bias,
                                                  const float* __restrict__ W,
                                                  unsigned short* __restrict__ UH,
                                                  float* __restrict__ SP) {
    int it = blockIdx.x, bt = blockIdx.y;
    int i0 = it * 8, b0 = bt * 64;
    int og = threadIdx.x & 3, b_l = threadIdx.x >> 2;
    int b = b0 + b_l;
    float acc[10][4];
#pragma unroll
    for (int j = 0; j < 10; ++j)
#pragma unroll
        for (int o = 0; o < 4; ++o) acc[j][o] = 0.f;
#pragma unroll
    for (int li = 0; li < 8; ++li) {
        int i = i0 + li;
        int cap = i / 36, posi = i - cap * 36;
        const float* p0 = pp + ((size_t)posi * 256 + b) * 256 + cap * 8;
        float4 pa = ((const float4*)p0)[0];
        float4 pb = ((const float4*)p0)[1];
        const float* bs = bias + cap * 8;
        float s8[8] = {pa.x + bs[0], pa.y + bs[1], pa.z + bs[2], pa.w + bs[3],
                       pb.x + bs[4], pb.y + bs[5], pb.z + bs[6], pb.w + bs[7]};
        float sq = 0.f;
#pragma unroll
        for (int d = 0; d < 8; ++d) sq += s8[d] * s8[d];
        float scale = sq / ((1.0f + sq) * sqrtf(sq + 1e-8f));
        float u8[8];
#pragma unroll
        for (int d = 0; d < 8; ++d) u8[d] = scale * s8[d];
        const float* Wi = W + (size_t)i * 1280 + og * 4;
#pragma unroll
        for (int j = 0; j < 10; ++j) {
            float o4[4] = {0.f, 0.f, 0.f, 0.f};
#pragma unroll
            for (int d = 0; d < 8; ++d) {
                float4 wv = *(const float4*)(Wi + d * 160 + j * 16);
                o4[0] += u8[d] * wv.x; o4[1] += u8[d] * wv.y;
                o4[2] += u8[d] * wv.z; o4[3] += u8[d] * wv.w;
            }
            u16x4 h;
#pragma unroll
            for (int o = 0; o < 4; ++o) { h[o] = f2bf(o4[o]); acc[j][o] += o4[o]; }
            *(u16x4*)(UH + ((size_t)(i * 10 + j) * 256 + b) * 16 + og * 4) = h;
        }
    }
    float* sp = SP + ((size_t)it * 256 + b) * 160 + og * 4;
#pragma unroll
    for (int j = 0; j < 10; ++j)
        *(float4*)(sp + j * 16) = make_float4(0.1f * acc[j][0], 0.1f * acc[j][1],
                                              0.1f * acc[j][2], 0.1f * acc[j][3]);
}

// ---------------- fused routing: logits (+)= <u_hat,v>; softmax; s-partials ----------------
__global__ __launch_bounds__(256) void k_route_as(float* __restrict__ L,
                                                  const unsigned short* __restrict__ UH,
                                                  const float* __restrict__ V,
                                                  float* __restrict__ SP,
                                                  int add, int storeL) {
    __shared__ float VL[64][165];
    __shared__ float LG[64][81];
    int it = blockIdx.x, bt = blockIdx.y;
    int b0 = bt * 64, i0 = it * 8;
    int b_l = threadIdx.x & 63;
    int ig = __builtin_amdgcn_readfirstlane((int)(threadIdx.x >> 6));
    int b_r = threadIdx.x >> 2, part = threadIdx.x & 3;
    {
        const float4* vsrc = (const float4*)(V + (size_t)(b0 + b_r) * 160 + part * 40);
#pragma unroll
        for (int q = 0; q < 10; ++q) {
            float4 vv = vsrc[q]; int c = part * 40 + q * 4;
            VL[b_r][c] = vv.x; VL[b_r][c + 1] = vv.y; VL[b_r][c + 2] = vv.z; VL[b_r][c + 3] = vv.w;
        }
        if (add) {
            const float4* lsrc = (const float4*)(L + (size_t)(b0 + b_r) * 11520 + i0 * 10 + part * 20);
#pragma unroll
            for (int q = 0; q < 5; ++q) {
                float4 t = lsrc[q]; int c = part * 20 + q * 4;
                LG[b_r][c] = t.x; LG[b_r][c + 1] = t.y; LG[b_r][c + 2] = t.z; LG[b_r][c + 3] = t.w;
            }
        }
    }
    __syncthreads();
#pragma unroll
    for (int ii = 0; ii < 2; ++ii) {
        int il = ig * 2 + ii;
        int i = i0 + il;
        const unsigned short* up = UH + ((size_t)i * 10 * 256 + b0 + b_l) * 16;
#pragma unroll
        for (int j = 0; j < 10; ++j) {
            u16x8 ua = *(const u16x8*)(up + j * 4096);
            u16x8 ub = *(const u16x8*)(up + j * 4096 + 8);
            float a = 0.f;
#pragma unroll
            for (int o = 0; o < 8; ++o) a += bf2f(ua[o]) * VL[b_l][j * 16 + o];
#pragma unroll
            for (int o = 0; o < 8; ++o) a += bf2f(ub[o]) * VL[b_l][j * 16 + 8 + o];
            float base = add ? LG[b_l][il * 10 + j] : 0.f;
            LG[b_l][il * 10 + j] = base + a;
        }
    }
    __syncthreads();
    if (storeL) {
        float4* ldst = (float4*)(L + (size_t)(b0 + b_r) * 11520 + i0 * 10 + part * 20);
#pragma unroll
        for (int q = 0; q < 5; ++q) {
            int c = part * 20 + q * 4;
            ldst[q] = make_float4(LG[b_r][c], LG[b_r][c + 1], LG[b_r][c + 2], LG[b_r][c + 3]);
        }
    }
    float acc[10][4];
#pragma unroll
    for (int j = 0; j < 10; ++j)
#pragma unroll
        for (int o = 0; o < 4; ++o) acc[j][o] = 0.f;
    for (int li = 0; li < 8; ++li) {
        float lg[10];
#pragma unroll
        for (int j = 0; j < 10; ++j) lg[j] = LG[b_l][li * 10 + j];
        float m = lg[0];
#pragma unroll
        for (int j = 1; j < 10; ++j) m = fmaxf(m, lg[j]);
        float e[10], ssum = 0.f;
#pragma unroll
        for (int j = 0; j < 10; ++j) { e[j] = __expf(lg[j] - m); ssum += e[j]; }
        float inv = 1.0f / ssum;
        const unsigned short* up = UH + ((size_t)(i0 + li) * 10 * 256 + b0 + b_l) * 16 + ig * 4;
#pragma unroll
        for (int j = 0; j < 10; ++j) {
            float cj = e[j] * inv;
            u16x4 t = *(const u16x4*)(up + j * 4096);
#pragma unroll
            for (int o = 0; o < 4; ++o) acc[j][o] += cj * bf2f(t[o]);
        }
    }
    float* sp = SP + ((size_t)it * 256 + b0 + b_l) * 160 + ig * 4;
#pragma unroll
    for (int j = 0; j < 10; ++j)
        *(float4*)(sp + j * 16) = make_float4(acc[j][0], acc[j][1], acc[j][2], acc[j][3]);
}

// ---------------- routing: reduce partials + squash -> v ----------------
__global__ __launch_bounds__(256) void k_route_v(const float* __restrict__ SP,
                                                 float* __restrict__ vout) {
    int n = blockIdx.x * 256 + threadIdx.x;  // 40960
    float ssum = 0.f;
    for (int t = 0; t < 144; ++t) ssum += SP[(size_t)t * 40960 + n];
    float sq = ssum * ssum;
    float tot = sq;
#pragma unroll
    for (int mask = 1; mask < 16; mask <<= 1) tot += __shfl_xor(tot, mask, 64);
    float scale = tot / ((1.0f + tot) * sqrtf(tot + 1e-8f));
    vout[n] = scale * ssum;
}

// ---------------- launcher ----------------
extern "C" void kernel_launch(void* const* d_in, const int* in_sizes, int n_in,
                              void* d_out, int out_size, void* d_ws, size_t ws_size,
                              hipStream_t stream) {
    (void)in_sizes; (void)n_in; (void)out_size; (void)ws_size;
    const float* x   = (const float*)d_in[0];
    const float* c1w = (const float*)d_in[1];
    const float* c1b = (const float*)d_in[2];
    const float* pcw = (const float*)d_in[3];
    const float* pcb = (const float*)d_in[4];
    const float* Wd  = (const float*)d_in[5];
    float* out = (float*)d_out;
    char* wsb  = (char*)d_ws;

    unsigned short* uh = (unsigned short*)(wsb + UHAT_OFF);
    _Float16* w6 = (_Float16*)(wsb + W6_OFF);
    _Float16* h3 = (_Float16*)(wsb + H3_OFF);
    float* wT1 = (float*)(wsb + WT1_OFF);
    float* pp  = (float*)(wsb + PP_OFF);
    float* sp  = (float*)(wsb + SP_OFF);
    float* lg  = (float*)(wsb + L_OFF);
    float* v   = (float*)(wsb + V_OFF);

    hipMemsetAsync(pp, 0, (size_t)9216 * 256 * sizeof(float), stream);
    // zero tap 81 of w6 (all ks/og): 81*8*16*512 halfs onward, 128KB
    hipMemsetAsync(w6 + (size_t)81 * 65536, 0, 131072, stream);

    k_prep_w<<<dim3(256, 4), 256, 0, stream>>>(pcw, w6);
    k_transpose_w1<<<81, 256, 0, stream>>>(c1w, wT1);
    k_conv1<<<dim3(10, 256), 256, 0, stream>>>(x, wT1, c1b, h3);
    k_conv2_mfma<<<dim3(36, 2, 8), 256, 0, stream>>>(h3, w6, pp);
    k_postconv<<<dim3(144, 4), 256, 0, stream>>>(pp, pcb, Wd, uh, sp);

    // iter 0 tail: v from s0-partials
    k_route_v<<<160, 256, 0, stream>>>(sp, v);
    // iter 1 (fused agree+softmax+s); logits were zero -> add=0, store for iter 2
    k_route_as<<<dim3(144, 4), 256, 0, stream>>>(lg, uh, v, sp, 0, 1);
    k_route_v<<<160, 256, 0, stream>>>(sp, v);
    // iter 2 (fused); last use of logits -> no store
    k_route_as<<<dim3(144, 4), 256, 0, stream>>>(lg, uh, v, sp, 1, 0);
    k_route_v<<<160, 256, 0, stream>>>(sp, out);
}

// Round 9
// 477.157 us; speedup vs baseline: 1.0961x; 1.0961x over previous
//
#include <hip/hip_runtime.h>
#include <hip/hip_bf16.h>

// ---------------- problem constants ----------------
#define NI 1152
// conv2 GEMM view: M=9216 as (pos,b); N=256 (oc); K=82 taps (81+1 zero) x 256 ic

typedef __attribute__((ext_vector_type(8))) _Float16 f16x8;
typedef __attribute__((ext_vector_type(4))) float f32x4;
typedef __attribute__((ext_vector_type(8))) unsigned short u16x8;
typedef __attribute__((ext_vector_type(4))) unsigned short u16x4;

// ws layout (bytes). Phase-1 buffers (w5,h3,wT1) alias under uhat; pp is OUTSIDE
// (postconv reads pp while writing UH).
static const size_t UHAT_OFF = 0;                        // bf16 1152*10*256*16 = 94,371,840
static const size_t W5_OFF   = 0;                        // f16 82*8*2*4*128*8 = 10,747,904 B
static const size_t H3_OFF   = 10750976UL;               // f16 8*400*4*256*8 = 52,428,800 B
static const size_t WT1_OFF  = 63179776UL;               // f32 81*256 (ends 63,262,720 < UHAT end)
static const size_t PP_OFF   = 94371840UL;               // f32 9216*256 = 9,437,184
static const size_t SP_OFF   = 103809024UL;              // f32 144*256*160 = 23,592,960
static const size_t L_OFF    = 127401984UL;              // f32 256*1152*10 = 11,796,480
static const size_t V_OFF    = 139198464UL;              // f32 256*160

__device__ __forceinline__ unsigned short f2bf(float x) {
    unsigned u = __builtin_bit_cast(unsigned, x);
    u += 0x7fffu + ((u >> 16) & 1u);
    return (unsigned short)(u >> 16);
}
__device__ __forceinline__ float bf2f(unsigned short h) {
    return __builtin_bit_cast(float, (unsigned)h << 16);
}
__device__ __forceinline__ void atomAddF(float* p, float v) {
    __hip_atomic_fetch_add(p, v, __ATOMIC_RELAXED, __HIP_MEMORY_SCOPE_AGENT);
}

#define GLD16(gsrc, ldst)                                                      \
    __builtin_amdgcn_global_load_lds(                                          \
        (__attribute__((address_space(1))) const void*)(gsrc),                 \
        (__attribute__((address_space(3))) void*)(ldst), 16, 0, 0)

// ---------------- weight prep: pc_w [oc][ic*81+tap] -> w5 (Bs-image order) ----------------
// w5 linear: ((((tap*8+ks)*2+nt)*4 + p)*128 + row)*8 + icl,  oc=nt*128+row, ic=ks*32+p*8+icl
__global__ __launch_bounds__(256) void k_prep_w(const float* __restrict__ pcw,
                                                _Float16* __restrict__ w5) {
    __shared__ float sl[5184];
    int oc  = blockIdx.x;       // 256
    int ic0 = blockIdx.y * 64;  // 4 chunks
    const float* src = pcw + (size_t)oc * 20736 + (size_t)ic0 * 81;
    for (int j = threadIdx.x; j < 5184; j += 256) sl[j] = src[j];
    __syncthreads();
    int nt = oc >> 7, row = oc & 127;
    for (int t = threadIdx.x; t < 5184; t += 256) {
        int tap = t >> 6, i = t & 63;
        int ic = ic0 + i;
        int ks = ic >> 5, p = (ic >> 3) & 3, icl = ic & 7;
        w5[((size_t)(((tap * 8 + ks) * 2 + nt) * 4 + p) * 128 + row) * 8 + icl] =
            (_Float16)sl[i * 81 + tap];
    }
}

// conv1_w [oc][81] -> wT1 [t][oc]
__global__ void k_transpose_w1(const float* __restrict__ w, float* __restrict__ wT) {
    int t = blockIdx.x, oc = threadIdx.x;
    wT[t * 256 + oc] = w[oc * 81 + t];
}

// ---------------- conv1 + relu -> h3[ks][y][x][p][b][8] f16 ----------------
__global__ __launch_bounds__(256) void k_conv1(const float* __restrict__ x,
                                               const float* __restrict__ wT1,
                                               const float* __restrict__ bias,
                                               _Float16* __restrict__ h3) {
    __shared__ _Float16 hs[2][20][256];  // 20KB
    int b  = blockIdx.y;    // 256
    int rp = blockIdx.x;    // 10 row-pairs
    int oc = threadIdx.x;   // 256
    int oy0 = rp * 2;
    const float* xb = x + (size_t)b * 784;
    float bv = bias[oc];
    float acc0[20], acc1[20];
#pragma unroll
    for (int i = 0; i < 20; ++i) { acc0[i] = bv; acc1[i] = bv; }
    for (int ky = 0; ky < 9; ++ky) {
        const float* r0 = xb + (oy0 + ky) * 28;
        const float* r1 = r0 + 28;
        float x0[28], x1[28];
#pragma unroll
        for (int c = 0; c < 28; ++c) { x0[c] = r0[c]; x1[c] = r1[c]; }
#pragma unroll
        for (int kx = 0; kx < 9; ++kx) {
            float w = wT1[(ky * 9 + kx) * 256 + oc];
#pragma unroll
            for (int px = 0; px < 20; ++px) {
                acc0[px] += x0[px + kx] * w;
                acc1[px] += x1[px + kx] * w;
            }
        }
    }
#pragma unroll
    for (int px = 0; px < 20; ++px) {
        hs[0][px][oc] = (_Float16)fmaxf(acc0[px], 0.f);
        hs[1][px][oc] = (_Float16)fmaxf(acc1[px], 0.f);
    }
    __syncthreads();
    for (int cid = threadIdx.x; cid < 1280; cid += 256) {
        int kp = cid & 31;          // ks*4 + p
        int pos = cid >> 5;         // ry*20 + px
        int ry = pos / 20, px2 = pos % 20;
        int ks = kp >> 2, p = kp & 3;
        f16x8 val = *(const f16x8*)&hs[ry][px2][ks * 32 + p * 8];
        _Float16* dst = h3 + ((size_t)((ks * 400 + (oy0 + ry) * 20 + px2) * 4 + p) * 256 + b) * 8;
        *(f16x8*)dst = val;
    }
}

// ---------------- primary caps conv: f16 MFMA implicit GEMM (R6 structure) ----------------
// grid (72 mt=pos*2+bhalf, 2 nt, 8 ks); block 256 = 4 waves (2x2); 128x128 tile, BK=64.
// All GLD16s read contiguous 1KB spans (operands pre-packed in LDS-image order).
__global__ __launch_bounds__(256, 4) void k_conv2_mfma(
    const _Float16* __restrict__ h3, const _Float16* __restrict__ w5,
    float* __restrict__ pp) {
    __shared__ _Float16 As[8192], Bs[8192];
    const int mt = blockIdx.x, nt = blockIdx.y, ks = blockIdx.z;
    const int pos = mt >> 1, bhalf = mt & 1;
    const int py = pos / 6, px = pos % 6;
    const int l = threadIdx.x & 63;
    const int w = __builtin_amdgcn_readfirstlane((int)(threadIdx.x >> 6));
    const int wm = w >> 1, wn = w & 1;

    f32x4 acc[4][4];
    const f32x4 z = {0.f, 0.f, 0.f, 0.f};
#pragma unroll
    for (int mi = 0; mi < 4; ++mi)
#pragma unroll
        for (int ni = 0; ni < 4; ++ni) acc[mi][ni] = z;

    const int ch = (l >> 4) * 1024;           // k-chunk plane (shorts)
    const int am = (wm * 64 + (l & 15)) * 8;  // a-frag row offset within plane
    const int bn = (wn * 64 + (l & 15)) * 8;  // b-frag row offset within plane
    const int lds_off = w * 1024 + l * 8;

    for (int it = 0; it < 41; ++it) {
        const int t0 = 2 * it, t1 = t0 + 1;
        const int tA1 = (t1 > 80) ? 80 : t1;  // clamp A address; B tap 81 is zero-padded
#pragma unroll
        for (int tl = 0; tl < 2; ++tl) {
            const int tap  = tl ? t1 : t0;
            const int tapA = tl ? tA1 : t0;
            const int y = 2 * py + tapA / 9, xx = 2 * px + tapA % 9;
            // wave w stages plane w of both operands
            const _Float16* asrc = h3 + ((size_t)(ks * 400 + y * 20 + xx) * 4 + w) * 2048 +
                                   bhalf * 1024 + l * 8;
            const _Float16* bsrc = w5 + ((size_t)((tap * 8 + ks) * 2 + nt)) * 4096 + lds_off;
            GLD16(asrc,       As + tl * 4096 + lds_off);
            GLD16(asrc + 512, As + tl * 4096 + lds_off + 512);
            GLD16(bsrc,       Bs + tl * 4096 + lds_off);
            GLD16(bsrc + 512, Bs + tl * 4096 + lds_off + 512);
        }
        __syncthreads();
#pragma unroll
        for (int s = 0; s < 2; ++s) {
            const int pb = s * 4096 + ch;
            f16x8 a[4], b[4];
#pragma unroll
            for (int i = 0; i < 4; ++i) {
                a[i] = *(const f16x8*)(As + pb + am + i * 128);
                b[i] = *(const f16x8*)(Bs + pb + bn + i * 128);
            }
#pragma unroll
            for (int mi = 0; mi < 4; ++mi)
#pragma unroll
                for (int ni = 0; ni < 4; ++ni)
                    acc[mi][ni] = __builtin_amdgcn_mfma_f32_16x16x32_f16(a[mi], b[ni], acc[mi][ni], 0, 0, 0);
        }
        __syncthreads();
    }
    // epilogue: D[m][n], m=(lane>>4)*4+reg, n=lane&15; atomic split-K reduce
    const int row0 = (l >> 4) * 4;
    const int ncol = l & 15;
#pragma unroll
    for (int mi = 0; mi < 4; ++mi)
#pragma unroll
        for (int ni = 0; ni < 4; ++ni) {
            int n = nt * 128 + wn * 64 + ni * 16 + ncol;
#pragma unroll
            for (int reg = 0; reg < 4; ++reg) {
                int m = pos * 256 + bhalf * 128 + wm * 64 + mi * 16 + row0 + reg;
                atomAddF(&pp[(size_t)m * 256 + n], acc[mi][ni][reg]);
            }
        }
}

// ---------------- fused: bias+squash -> u_hat(bf16 UH) + s0-partials ----------------
// grid (144 it, 4 bt); block 256 = 64 b x 4 og (og = tid&3 -> coalesced UH writes).
__global__ __launch_bounds__(256) void k_postconv(const float* __restrict__ pp,
                                                  const float* __restrict__ bias,
                                                  const float* __restrict__ W,
                                                  unsigned short* __restrict__ UH,
                                                  float* __restrict__ SP) {
    int it = blockIdx.x, bt = blockIdx.y;
    int i0 = it * 8, b0 = bt * 64;
    int og = threadIdx.x & 3, b_l = threadIdx.x >> 2;
    int b = b0 + b_l;
    float acc[10][4];
#pragma unroll
    for (int j = 0; j < 10; ++j)
#pragma unroll
        for (int o = 0; o < 4; ++o) acc[j][o] = 0.f;
#pragma unroll
    for (int li = 0; li < 8; ++li) {
        int i = i0 + li;
        int cap = i / 36, posi = i - cap * 36;
        const float* p0 = pp + ((size_t)posi * 256 + b) * 256 + cap * 8;
        float4 pa = ((const float4*)p0)[0];
        float4 pb = ((const float4*)p0)[1];
        const float* bs = bias + cap * 8;
        float s8[8] = {pa.x + bs[0], pa.y + bs[1], pa.z + bs[2], pa.w + bs[3],
                       pb.x + bs[4], pb.y + bs[5], pb.z + bs[6], pb.w + bs[7]};
        float sq = 0.f;
#pragma unroll
        for (int d = 0; d < 8; ++d) sq += s8[d] * s8[d];
        float scale = sq / ((1.0f + sq) * sqrtf(sq + 1e-8f));
        float u8[8];
#pragma unroll
        for (int d = 0; d < 8; ++d) u8[d] = scale * s8[d];
        const float* Wi = W + (size_t)i * 1280 + og * 4;
#pragma unroll
        for (int j = 0; j < 10; ++j) {
            float o4[4] = {0.f, 0.f, 0.f, 0.f};
#pragma unroll
            for (int d = 0; d < 8; ++d) {
                float4 wv = *(const float4*)(Wi + d * 160 + j * 16);
                o4[0] += u8[d] * wv.x; o4[1] += u8[d] * wv.y;
                o4[2] += u8[d] * wv.z; o4[3] += u8[d] * wv.w;
            }
            u16x4 h;
#pragma unroll
            for (int o = 0; o < 4; ++o) { h[o] = f2bf(o4[o]); acc[j][o] += o4[o]; }
            *(u16x4*)(UH + ((size_t)(i * 10 + j) * 256 + b) * 16 + og * 4) = h;
        }
    }
    float* sp = SP + ((size_t)it * 256 + b) * 160 + og * 4;
#pragma unroll
    for (int j = 0; j < 10; ++j)
        *(float4*)(sp + j * 16) = make_float4(0.1f * acc[j][0], 0.1f * acc[j][1],
                                              0.1f * acc[j][2], 0.1f * acc[j][3]);
}

// ---------------- fused routing: logits (+)= <u_hat,v>; softmax; s-partials ----------------
__global__ __launch_bounds__(256) void k_route_as(float* __restrict__ L,
                                                  const unsigned short* __restrict__ UH,
                                                  const float* __restrict__ V,
                                                  float* __restrict__ SP,
                                                  int add, int storeL) {
    __shared__ float VL[64][165];
    __shared__ float LG[64][81];
    int it = blockIdx.x, bt = blockIdx.y;
    int b0 = bt * 64, i0 = it * 8;
    int b_l = threadIdx.x & 63;
    int ig = __builtin_amdgcn_readfirstlane((int)(threadIdx.x >> 6));
    int b_r = threadIdx.x >> 2, part = threadIdx.x & 3;
    {
        const float4* vsrc = (const float4*)(V + (size_t)(b0 + b_r) * 160 + part * 40);
#pragma unroll
        for (int q = 0; q < 10; ++q) {
            float4 vv = vsrc[q]; int c = part * 40 + q * 4;
            VL[b_r][c] = vv.x; VL[b_r][c + 1] = vv.y; VL[b_r][c + 2] = vv.z; VL[b_r][c + 3] = vv.w;
        }
        if (add) {
            const float4* lsrc = (const float4*)(L + (size_t)(b0 + b_r) * 11520 + i0 * 10 + part * 20);
#pragma unroll
            for (int q = 0; q < 5; ++q) {
                float4 t = lsrc[q]; int c = part * 20 + q * 4;
                LG[b_r][c] = t.x; LG[b_r][c + 1] = t.y; LG[b_r][c + 2] = t.z; LG[b_r][c + 3] = t.w;
            }
        }
    }
    __syncthreads();
#pragma unroll
    for (int ii = 0; ii < 2; ++ii) {
        int il = ig * 2 + ii;
        int i = i0 + il;
        const unsigned short* up = UH + ((size_t)i * 10 * 256 + b0 + b_l) * 16;
#pragma unroll
        for (int j = 0; j < 10; ++j) {
            u16x8 ua = *(const u16x8*)(up + j * 4096);
            u16x8 ub = *(const u16x8*)(up + j * 4096 + 8);
            float a = 0.f;
#pragma unroll
            for (int o = 0; o < 8; ++o) a += bf2f(ua[o]) * VL[b_l][j * 16 + o];
#pragma unroll
            for (int o = 0; o < 8; ++o) a += bf2f(ub[o]) * VL[b_l][j * 16 + 8 + o];
            float base = add ? LG[b_l][il * 10 + j] : 0.f;
            LG[b_l][il * 10 + j] = base + a;
        }
    }
    __syncthreads();
    if (storeL) {
        float4* ldst = (float4*)(L + (size_t)(b0 + b_r) * 11520 + i0 * 10 + part * 20);
#pragma unroll
        for (int q = 0; q < 5; ++q) {
            int c = part * 20 + q * 4;
            ldst[q] = make_float4(LG[b_r][c], LG[b_r][c + 1], LG[b_r][c + 2], LG[b_r][c + 3]);
        }
    }
    float acc[10][4];
#pragma unroll
    for (int j = 0; j < 10; ++j)
#pragma unroll
        for (int o = 0; o < 4; ++o) acc[j][o] = 0.f;
    for (int li = 0; li < 8; ++li) {
        float lg[10];
#pragma unroll
        for (int j = 0; j < 10; ++j) lg[j] = LG[b_l][li * 10 + j];
        float m = lg[0];
#pragma unroll
        for (int j = 1; j < 10; ++j) m = fmaxf(m, lg[j]);
        float e[10], ssum = 0.f;
#pragma unroll
        for (int j = 0; j < 10; ++j) { e[j] = __expf(lg[j] - m); ssum += e[j]; }
        float inv = 1.0f / ssum;
        const unsigned short* up = UH + ((size_t)(i0 + li) * 10 * 256 + b0 + b_l) * 16 + ig * 4;
#pragma unroll
        for (int j = 0; j < 10; ++j) {
            float cj = e[j] * inv;
            u16x4 t = *(const u16x4*)(up + j * 4096);
#pragma unroll
            for (int o = 0; o < 4; ++o) acc[j][o] += cj * bf2f(t[o]);
        }
    }
    float* sp = SP + ((size_t)it * 256 + b0 + b_l) * 160 + ig * 4;
#pragma unroll
    for (int j = 0; j < 10; ++j)
        *(float4*)(sp + j * 16) = make_float4(acc[j][0], acc[j][1], acc[j][2], acc[j][3]);
}

// ---------------- routing: reduce partials + squash -> v ----------------
__global__ __launch_bounds__(256) void k_route_v(const float* __restrict__ SP,
                                                 float* __restrict__ vout) {
    int n = blockIdx.x * 256 + threadIdx.x;  // 40960
    float ssum = 0.f;
    for (int t = 0; t < 144; ++t) ssum += SP[(size_t)t * 40960 + n];
    float sq = ssum * ssum;
    float tot = sq;
#pragma unroll
    for (int mask = 1; mask < 16; mask <<= 1) tot += __shfl_xor(tot, mask, 64);
    float scale = tot / ((1.0f + tot) * sqrtf(tot + 1e-8f));
    vout[n] = scale * ssum;
}

// ---------------- launcher ----------------
extern "C" void kernel_launch(void* const* d_in, const int* in_sizes, int n_in,
                              void* d_out, int out_size, void* d_ws, size_t ws_size,
                              hipStream_t stream) {
    (void)in_sizes; (void)n_in; (void)out_size; (void)ws_size;
    const float* x   = (const float*)d_in[0];
    const float* c1w = (const float*)d_in[1];
    const float* c1b = (const float*)d_in[2];
    const float* pcw = (const float*)d_in[3];
    const float* pcb = (const float*)d_in[4];
    const float* Wd  = (const float*)d_in[5];
    float* out = (float*)d_out;
    char* wsb  = (char*)d_ws;

    unsigned short* uh = (unsigned short*)(wsb + UHAT_OFF);
    _Float16* w5 = (_Float16*)(wsb + W5_OFF);
    _Float16* h3 = (_Float16*)(wsb + H3_OFF);
    float* wT1 = (float*)(wsb + WT1_OFF);
    float* pp  = (float*)(wsb + PP_OFF);
    float* sp  = (float*)(wsb + SP_OFF);
    float* lg  = (float*)(wsb + L_OFF);
    float* v   = (float*)(wsb + V_OFF);

    hipMemsetAsync(pp, 0, (size_t)9216 * 256 * sizeof(float), stream);
    // zero tap 81 of w5 (all ks/nt/p): one tap stride = 65536 halfs = 128KB
    hipMemsetAsync(w5 + (size_t)81 * 65536, 0, (size_t)65536 * sizeof(_Float16), stream);

    k_prep_w<<<dim3(256, 4), 256, 0, stream>>>(pcw, w5);
    k_transpose_w1<<<81, 256, 0, stream>>>(c1w, wT1);
    k_conv1<<<dim3(10, 256), 256, 0, stream>>>(x, wT1, c1b, h3);
    k_conv2_mfma<<<dim3(72, 2, 8), 256, 0, stream>>>(h3, w5, pp);
    k_postconv<<<dim3(144, 4), 256, 0, stream>>>(pp, pcb, Wd, uh, sp);

    // iter 0 tail: v from s0-partials
    k_route_v<<<160, 256, 0, stream>>>(sp, v);
    // iter 1 (fused agree+softmax+s); logits were zero -> add=0, store for iter 2
    k_route_as<<<dim3(144, 4), 256, 0, stream>>>(lg, uh, v, sp, 0, 1);
    k_route_v<<<160, 256, 0, stream>>>(sp, v);
    // iter 2 (fused); last use of logits -> no store
    k_route_as<<<dim3(144, 4), 256, 0, stream>>>(lg, uh, v, sp, 1, 0);
    k_route_v<<<160, 256, 0, stream>>>(sp, out);
}